// Round 3
// baseline (750.990 us; speedup 1.0000x reference)
//
#include <hip/hip_runtime.h>

// NeRF tiny MLP, fully fused. R5: zero-LDS activation chaining using ONLY the
// HW-verified mfma_f32_16x16x32_f16 layouts (R4's 16x16x16 K=16 chaining bet
// on an unverified B-layout and failed correctness).
// Derivation: D lane (q,c) holds (feature 16mb+4q+r, point c); a K=32 B-frag
// lane (q,c) needs (k=8q+j, point c) -- same point class per lane, so NO
// cross-lane movement is needed: B1=concat(x[0],x[1]), B2=concat(x[2],x[3])
// (register packing only), and the CONSUMER layer's weight-fragment k-rows
// are permuted at staging time to match where features physically sit:
//   k-slot 32u+8q+j  <->  feature 32u + 16*(j>>2) + 4q + (j&3)
// Weights are staged from global with arbitrary indexing -> permutation free.
//   - activations never touch LDS (no ds_writes, no in-loop barriers)
//   - enc loads go straight from global into K=32 register layout; dense and
//     color outputs end in q==0 lanes -> direct float4 global store
//   - bias pre-loaded into the MFMA C-operand (broadcast LDS reads)
// mfma 16x16x32 f16 layouts (q=lane>>4, c=lane&15) [verified by R3 kernel]:
//   A[m=c][k=8q+j]  B[k=8q+j][n=c]  D[row=4q+r][col=c]

#define WAVES_PER_BLOCK 8
#define BLOCK 512
#define GRID 512
#define NFRAG 40

typedef _Float16 half8 __attribute__((ext_vector_type(8)));
typedef _Float16 half4 __attribute__((ext_vector_type(4)));
typedef float float4v __attribute__((ext_vector_type(4)));
typedef float float4u __attribute__((ext_vector_type(4), aligned(4)));  // enc rows only 4B-aligned

#define CAT8(a, b) __builtin_shufflevector((a), (b), 0, 1, 2, 3, 4, 5, 6, 7)

// k-slot (32u + 8q + j) -> logical input-feature index, for layers whose
// input is a chained MFMA output consumed as concat(x[2u], x[2u+1]).
__device__ __forceinline__ int permk(int u, int q, int j) {
  return 32 * u + 16 * (j >> 2) + 4 * q + (j & 3);
}

// Weight fragment catalog (16B/lane slots in s_w), all K=32 A-frags:
//  f 0..3   L1  Win (32x64)  standard k:   Win[(8q+j)*64 + 16f + c]
//  f 4..11  L2  W0m (64x64)  perm k:       W0m[permk(u,q,j)*64 + 16mb + c]
//  f 12..13 L3  Wd  (64x16)  perm k:       Wd[permk(u,q,j)*16 + c]
//  f 14..21 L4  Wc  (54x64)  (mb,u):
//     u=0 pairs B1=concat(xh, xe16): j<4: h-slot hs=4q+j (hs==0 is the dense
//         slot -> zero row; else Wc[hs-1]); j>=4: e=32+4q+(j-4): e<39 ->
//         Wc[15+e] else 0.
//     u=1 pairs B2=xe32 (enc feats 8q+j): Wc[(15+8q+j)*64 + 16mb + c]
//  f 22..29 L5  W1a perm k | f 30..37 L6  W1b perm k
//  f 38..39 L7  Wo  (64x3)  perm k, cols padded 3->16
__device__ half8 make_frag(int f, int q, int c,
                           const float* Win, const float* W0m, const float* Wd,
                           const float* Wc, const float* W1a, const float* W1b,
                           const float* Wo) {
  half8 r;
  if (f < 4) {
#pragma unroll
    for (int j = 0; j < 8; ++j)
      r[j] = (_Float16)Win[(size_t)(8 * q + j) * 64 + 16 * f + c];
    return r;
  }
  if (f < 12) {
    int mb = (f - 4) >> 1, u = (f - 4) & 1;
#pragma unroll
    for (int j = 0; j < 8; ++j)
      r[j] = (_Float16)W0m[(size_t)permk(u, q, j) * 64 + 16 * mb + c];
    return r;
  }
  if (f < 14) {
    int u = f - 12;
#pragma unroll
    for (int j = 0; j < 8; ++j)
      r[j] = (_Float16)Wd[(size_t)permk(u, q, j) * 16 + c];
    return r;
  }
  if (f < 22) {
    int mb = (f - 14) >> 1, u = (f - 14) & 1;
    if (u == 0) {
#pragma unroll
      for (int i = 0; i < 4; ++i) {
        int hs = 4 * q + i;           // h-slot: 0 is dense -> zero weight row
        r[i] = (hs == 0) ? (_Float16)0.f
                         : (_Float16)Wc[(size_t)(hs - 1) * 64 + 16 * mb + c];
        int e = 32 + 4 * q + i;       // enc features 32..38, pad 0
        r[4 + i] = (e < 39) ? (_Float16)Wc[(size_t)(15 + e) * 64 + 16 * mb + c]
                            : (_Float16)0.f;
      }
    } else {
#pragma unroll
      for (int j = 0; j < 8; ++j)     // enc features 0..31
        r[j] = (_Float16)Wc[(size_t)(15 + 8 * q + j) * 64 + 16 * mb + c];
    }
    return r;
  }
  if (f < 30) {
    int mb = (f - 22) >> 1, u = (f - 22) & 1;
#pragma unroll
    for (int j = 0; j < 8; ++j)
      r[j] = (_Float16)W1a[(size_t)permk(u, q, j) * 64 + 16 * mb + c];
    return r;
  }
  if (f < 38) {
    int mb = (f - 30) >> 1, u = (f - 30) & 1;
#pragma unroll
    for (int j = 0; j < 8; ++j)
      r[j] = (_Float16)W1b[(size_t)permk(u, q, j) * 64 + 16 * mb + c];
    return r;
  }
  {
    int u = f - 38;
#pragma unroll
    for (int j = 0; j < 8; ++j)
      r[j] = (c < 3) ? (_Float16)Wo[(size_t)permk(u, q, j) * 3 + c]
                     : (_Float16)0.f;
    return r;
  }
}

__global__ __launch_bounds__(BLOCK, 4) void nerf_fused(
    const float* __restrict__ emb, const float* __restrict__ enc,
    const float* __restrict__ Win, const float* __restrict__ bin,
    const float* __restrict__ W0m, const float* __restrict__ b0v,
    const float* __restrict__ Wd, const float* __restrict__ bd,
    const float* __restrict__ Wc, const float* __restrict__ bc,
    const float* __restrict__ W1a, const float* __restrict__ b1a,
    const float* __restrict__ W1b, const float* __restrict__ b1b,
    const float* __restrict__ Wo, const float* __restrict__ bo,
    float* __restrict__ out, int npts)
{
  __shared__ __align__(16) _Float16 s_w[NFRAG * 512];   // 40 KB: [frag][lane][8]
  __shared__ __align__(16) float s_bias[352];

  const int tid = threadIdx.x;
  const int wib = tid >> 6;
  const int lane = tid & 63;
  const int q = lane >> 4;
  const int c = lane & 15;

  // --- stage biases: L1=0(64) L2=64 L3=128(16) L4=144 L5=208 L6=272 L7=336(16)
  for (int i = tid; i < 352; i += BLOCK) {
    float v;
    if (i < 64) v = bin[i];
    else if (i < 128) v = b0v[i - 64];
    else if (i < 144) v = bd[i - 128];
    else if (i < 208) v = bc[i - 144];
    else if (i < 272) v = b1a[i - 208];
    else if (i < 336) v = b1b[i - 272];
    else v = (i - 336 < 3) ? bo[i - 336] : 0.f;
    s_bias[i] = v;
  }

  // --- stage weight fragments (each of 8 waves handles 5 frags)
  for (int f = wib * 5; f < wib * 5 + 5; ++f) {
    half8 r = make_frag(f, q, c, Win, W0m, Wd, Wc, W1a, W1b, Wo);
    *(half8*)&s_w[f * 512 + lane * 8] = r;
  }

  __syncthreads();  // only barrier in the kernel

  const int totalWaves = gridDim.x * WAVES_PER_BLOCK;
  const int waveId = blockIdx.x * WAVES_PER_BLOCK + wib;
  const int ntiles = npts >> 5;  // 32 points per tile

  int tile = waveId;
  if (tile >= ntiles) return;

#define RW8(f) (*(const half8*)&s_w[(f) * 512 + lane * 8])
#define MM32(w, b, cc) __builtin_amdgcn_mfma_f32_16x16x32_f16((w), (b), (cc), 0, 0, 0)

  // prologue prefetch (two point groups g=0,1; point = tile*32 + 16g + c)
  float4v e0[2], e1[2];
  float4u na0[2], na1[2], e2p[2];
#pragma unroll
  for (int g = 0; g < 2; ++g) e2p[g] = (float4u){0.f, 0.f, 0.f, 0.f};
#pragma unroll
  for (int g = 0; g < 2; ++g) {
    const float* ep = emb + (size_t)(tile * 32 + 16 * g + c) * 32 + 8 * q;
    e0[g] = *(const float4v*)ep;
    e1[g] = *(const float4v*)(ep + 4);
    const float* np = enc + (size_t)(tile * 32 + 16 * g + c) * 39;
    na0[g] = *(const float4u*)(np + 8 * q);
    na1[g] = *(const float4u*)(np + 8 * q + 4);
    if (q == 0) e2p[g] = *(const float4u*)(np + 32);
    else if (q == 1) { e2p[g][0] = np[36]; e2p[g][1] = np[37]; e2p[g][2] = np[38]; }
  }

  float4v a_[4][2];  // layer accumulators
  half4 x[4][2];     // chained fragments: x[mb][g] = features 16mb+4q+r, point 16g+c

  // 64->64 layer: B1=concat(x0,x1), B2=concat(x2,x3); weights perm-staged.
#define LAYER64(FB, BOFF) do { \
    half8 b1_[2], b2_[2]; \
    _Pragma("unroll") for (int g = 0; g < 2; ++g) { \
      b1_[g] = CAT8(x[0][g], x[1][g]); \
      b2_[g] = CAT8(x[2][g], x[3][g]); \
    } \
    _Pragma("unroll") for (int mb = 0; mb < 4; ++mb) { \
      float4v bb = *(const float4v*)&s_bias[(BOFF) + 16 * mb + 4 * q]; \
      half8 w0 = RW8((FB) + 2 * mb), w1 = RW8((FB) + 2 * mb + 1); \
      _Pragma("unroll") for (int g = 0; g < 2; ++g) { \
        float4v a = MM32(w0, b1_[g], bb); \
        a_[mb][g] = MM32(w1, b2_[g], a); \
      } \
    } \
    _Pragma("unroll") for (int mb = 0; mb < 4; ++mb) \
      _Pragma("unroll") for (int g = 0; g < 2; ++g) { \
        half4 h; \
        _Pragma("unroll") for (int r = 0; r < 4; ++r) \
          h[r] = (_Float16)fmaxf(a_[mb][g][r], 0.f); \
        x[mb][g] = h; \
      } \
  } while (0)

  for (; tile < ntiles; tile += totalWaves) {
    const int nt0 = tile + totalWaves;
    const int nextTile = (nt0 < ntiles) ? nt0 : tile;

    // ---- L1: emb(32) -> 64, B straight from prefetched regs (standard k)
    half8 bfe[2];
#pragma unroll
    for (int g = 0; g < 2; ++g)
#pragma unroll
      for (int j = 0; j < 4; ++j) { bfe[g][j] = (_Float16)e0[g][j]; bfe[g][4 + j] = (_Float16)e1[g][j]; }
    {  // prefetch next emb
#pragma unroll
      for (int g = 0; g < 2; ++g) {
        const float* ep = emb + (size_t)(nextTile * 32 + 16 * g + c) * 32 + 8 * q;
        e0[g] = *(const float4v*)ep;
        e1[g] = *(const float4v*)(ep + 4);
      }
    }
#pragma unroll
    for (int mb = 0; mb < 4; ++mb) {
      float4v bb = *(const float4v*)&s_bias[0 + 16 * mb + 4 * q];
      half8 w = RW8(mb);
#pragma unroll
      for (int g = 0; g < 2; ++g) a_[mb][g] = MM32(w, bfe[g], bb);
    }
#pragma unroll
    for (int mb = 0; mb < 4; ++mb)
#pragma unroll
      for (int g = 0; g < 2; ++g) {
        half4 h;
#pragma unroll
        for (int r = 0; r < 4; ++r) h[r] = (_Float16)fmaxf(a_[mb][g][r], 0.f);
        x[mb][g] = h;
      }

    // ---- L2: 64 -> 64
    LAYER64(4, 64);

    // ---- L3: 64 -> 16 (dense + h), no relu; output chains into L4
    float dense_[2];
    half4 xh[2];
    {
      half8 w0 = RW8(12), w1 = RW8(13);
      float4v bb = *(const float4v*)&s_bias[128 + 4 * q];
#pragma unroll
      for (int g = 0; g < 2; ++g) {
        half8 b1_ = CAT8(x[0][g], x[1][g]);
        half8 b2_ = CAT8(x[2][g], x[3][g]);
        float4v a = MM32(w0, b1_, bb);
        a = MM32(w1, b2_, a);
        dense_[g] = a[0];  // valid in q==0 lanes (feature 0)
#pragma unroll
        for (int r = 0; r < 4; ++r) xh[g][r] = (_Float16)a[r];  // features 4q+r
      }
    }

    // enc B-frags straight from prefetched regs (no LDS)
    half8 xe32[2];
    half4 xe16[2];
#pragma unroll
    for (int g = 0; g < 2; ++g) {
#pragma unroll
      for (int j = 0; j < 4; ++j) { xe32[g][j] = (_Float16)na0[g][j]; xe32[g][4 + j] = (_Float16)na1[g][j]; }
#pragma unroll
      for (int i = 0; i < 4; ++i) xe16[g][i] = (_Float16)e2p[g][i];
    }
    {  // prefetch next enc
#pragma unroll
      for (int g = 0; g < 2; ++g) {
        const float* np = enc + (size_t)(nextTile * 32 + 16 * g + c) * 39;
        na0[g] = *(const float4u*)(np + 8 * q);
        na1[g] = *(const float4u*)(np + 8 * q + 4);
        if (q == 0) e2p[g] = *(const float4u*)(np + 32);
        else if (q == 1) { e2p[g][0] = np[36]; e2p[g][1] = np[37]; e2p[g][2] = np[38]; }
      }
    }

    // ---- L4: [h(16 slots) | enc(39, split 7+32)] -> 64
#pragma unroll
    for (int mb = 0; mb < 4; ++mb) {
      float4v bb = *(const float4v*)&s_bias[144 + 16 * mb + 4 * q];
      half8 wA = RW8(14 + 2 * mb), wE = RW8(15 + 2 * mb);
#pragma unroll
      for (int g = 0; g < 2; ++g) {
        half8 bh = CAT8(xh[g], xe16[g]);
        float4v a = MM32(wA, bh, bb);
        a_[mb][g] = MM32(wE, xe32[g], a);
      }
    }
#pragma unroll
    for (int mb = 0; mb < 4; ++mb)
#pragma unroll
      for (int g = 0; g < 2; ++g) {
        half4 h;
#pragma unroll
        for (int r = 0; r < 4; ++r) h[r] = (_Float16)fmaxf(a_[mb][g][r], 0.f);
        x[mb][g] = h;
      }

    // ---- L5, L6: 64 -> 64
    LAYER64(22, 208);
    LAYER64(30, 272);

    // ---- L7: 64 -> 3 (padded 16), no relu; store direct from q==0 lanes
    {
      half8 w0 = RW8(38), w1 = RW8(39);
      float4v bb = *(const float4v*)&s_bias[336 + 4 * q];
#pragma unroll
      for (int g = 0; g < 2; ++g) {
        half8 b1_ = CAT8(x[0][g], x[1][g]);
        half8 b2_ = CAT8(x[2][g], x[3][g]);
        float4v a = MM32(w0, b1_, bb);
        a = MM32(w1, b2_, a);
        if (q == 0) {
          float4v o;
          o[0] = a[0]; o[1] = a[1]; o[2] = a[2]; o[3] = dense_[g];
          *(float4v*)(out + (size_t)(tile * 32 + 16 * g + c) * 4) = o;
        }
      }
    }
  }
#undef LAYER64
#undef RW8
#undef MM32
}

extern "C" void kernel_launch(void* const* d_in, const int* in_sizes, int n_in,
                              void* d_out, int out_size, void* d_ws, size_t ws_size,
                              hipStream_t stream) {
  (void)d_ws; (void)ws_size; (void)out_size;
  if (n_in < 16) return;
  const float* emb = (const float*)d_in[0];
  const float* enc = (const float*)d_in[1];
  const float* Win = (const float*)d_in[2];
  const float* bin = (const float*)d_in[3];
  const float* W0m = (const float*)d_in[4];
  const float* b0v = (const float*)d_in[5];
  const float* Wd  = (const float*)d_in[6];
  const float* bd  = (const float*)d_in[7];
  const float* Wc  = (const float*)d_in[8];
  const float* bc  = (const float*)d_in[9];
  const float* W1a = (const float*)d_in[10];
  const float* b1a = (const float*)d_in[11];
  const float* W1b = (const float*)d_in[12];
  const float* b1b = (const float*)d_in[13];
  const float* Wo  = (const float*)d_in[14];
  const float* bo  = (const float*)d_in[15];
  float* out = (float*)d_out;
  const int npts = in_sizes[0] / 32;

  nerf_fused<<<GRID, BLOCK, 0, stream>>>(emb, enc, Win, bin, W0m, b0v, Wd, bd,
                                         Wc, bc, W1a, b1a, W1b, b1b, Wo, bo,
                                         out, npts);
}

// Round 4
// 451.368 us; speedup vs baseline: 1.6638x; 1.6638x over previous
//
#include <hip/hip_runtime.h>

// NeRF tiny MLP, fully fused. R6: R5's zero-LDS chaining algorithm unchanged
// (it passed: absmax 2e-3, bank-conflicts 0), fix the REGISTER BUDGET.
// R5 post-mortem: __launch_bounds__(512,4) pinned the allocator to ~64 arch
// VGPRs (rocprof VGPR_Count=64); the register-resident activation+prefetch
// state (~120+ regs) spilled to scratch -> FETCH 1.36 GB / WRITE 577 MB of
// spill traffic, 540us memory-bound at 45% HBM. One change: BLOCK 256 with
// __launch_bounds__(256,2) (VGPR cap 256; R2 precedent: 88 VGPRs, no spill).
// Expected 3 blocks/CU (12 waves) - LDS 3x42.4KB=127KB fits.
// Derivation recap: D lane (q,c) holds (feature 16mb+4q+r, point c); a K=32
// B-frag lane (q,c) needs (k=8q+j, point c) -- same point class per lane, so
// chaining needs NO cross-lane movement: B1=concat(x[0],x[1]),
// B2=concat(x[2],x[3]), and the CONSUMER layer's weight k-rows are permuted
// at staging: k-slot 32u+8q+j <-> feature 32u+16*(j>>2)+4q+(j&3).
// mfma 16x16x32 f16 layouts (q=lane>>4, c=lane&15) [HW-verified]:
//   A[m=c][k=8q+j]  B[k=8q+j][n=c]  D[row=4q+r][col=c]

#define WAVES_PER_BLOCK 4
#define BLOCK 256
#define GRID 1024
#define NFRAG 40

typedef _Float16 half8 __attribute__((ext_vector_type(8)));
typedef _Float16 half4 __attribute__((ext_vector_type(4)));
typedef float float4v __attribute__((ext_vector_type(4)));
typedef float float4u __attribute__((ext_vector_type(4), aligned(4)));  // enc rows only 4B-aligned

#define CAT8(a, b) __builtin_shufflevector((a), (b), 0, 1, 2, 3, 4, 5, 6, 7)

// k-slot (32u + 8q + j) -> logical input-feature index, for layers whose
// input is a chained MFMA output consumed as concat(x[2u], x[2u+1]).
__device__ __forceinline__ int permk(int u, int q, int j) {
  return 32 * u + 16 * (j >> 2) + 4 * q + (j & 3);
}

// Weight fragment catalog (16B/lane slots in s_w), all K=32 A-frags:
//  f 0..3   L1  Win (32x64)  standard k:   Win[(8q+j)*64 + 16f + c]
//  f 4..11  L2  W0m (64x64)  perm k:       W0m[permk(u,q,j)*64 + 16mb + c]
//  f 12..13 L3  Wd  (64x16)  perm k:       Wd[permk(u,q,j)*16 + c]
//  f 14..21 L4  Wc  (54x64)  (mb,u):
//     u=0 pairs B1=concat(xh, xe16): j<4: h-slot hs=4q+j (hs==0 is the dense
//         slot -> zero row; else Wc[hs-1]); j>=4: e=32+4q+(j-4): e<39 ->
//         Wc[15+e] else 0.
//     u=1 pairs B2=xe32 (enc feats 8q+j): Wc[(15+8q+j)*64 + 16mb + c]
//  f 22..29 L5  W1a perm k | f 30..37 L6  W1b perm k
//  f 38..39 L7  Wo  (64x3)  perm k, cols padded 3->16
__device__ half8 make_frag(int f, int q, int c,
                           const float* Win, const float* W0m, const float* Wd,
                           const float* Wc, const float* W1a, const float* W1b,
                           const float* Wo) {
  half8 r;
  if (f < 4) {
#pragma unroll
    for (int j = 0; j < 8; ++j)
      r[j] = (_Float16)Win[(size_t)(8 * q + j) * 64 + 16 * f + c];
    return r;
  }
  if (f < 12) {
    int mb = (f - 4) >> 1, u = (f - 4) & 1;
#pragma unroll
    for (int j = 0; j < 8; ++j)
      r[j] = (_Float16)W0m[(size_t)permk(u, q, j) * 64 + 16 * mb + c];
    return r;
  }
  if (f < 14) {
    int u = f - 12;
#pragma unroll
    for (int j = 0; j < 8; ++j)
      r[j] = (_Float16)Wd[(size_t)permk(u, q, j) * 16 + c];
    return r;
  }
  if (f < 22) {
    int mb = (f - 14) >> 1, u = (f - 14) & 1;
    if (u == 0) {
#pragma unroll
      for (int i = 0; i < 4; ++i) {
        int hs = 4 * q + i;           // h-slot: 0 is dense -> zero weight row
        r[i] = (hs == 0) ? (_Float16)0.f
                         : (_Float16)Wc[(size_t)(hs - 1) * 64 + 16 * mb + c];
        int e = 32 + 4 * q + i;       // enc features 32..38, pad 0
        r[4 + i] = (e < 39) ? (_Float16)Wc[(size_t)(15 + e) * 64 + 16 * mb + c]
                            : (_Float16)0.f;
      }
    } else {
#pragma unroll
      for (int j = 0; j < 8; ++j)     // enc features 0..31
        r[j] = (_Float16)Wc[(size_t)(15 + 8 * q + j) * 64 + 16 * mb + c];
    }
    return r;
  }
  if (f < 30) {
    int mb = (f - 22) >> 1, u = (f - 22) & 1;
#pragma unroll
    for (int j = 0; j < 8; ++j)
      r[j] = (_Float16)W1a[(size_t)permk(u, q, j) * 64 + 16 * mb + c];
    return r;
  }
  if (f < 38) {
    int mb = (f - 30) >> 1, u = (f - 30) & 1;
#pragma unroll
    for (int j = 0; j < 8; ++j)
      r[j] = (_Float16)W1b[(size_t)permk(u, q, j) * 64 + 16 * mb + c];
    return r;
  }
  {
    int u = f - 38;
#pragma unroll
    for (int j = 0; j < 8; ++j)
      r[j] = (c < 3) ? (_Float16)Wo[(size_t)permk(u, q, j) * 3 + c]
                     : (_Float16)0.f;
    return r;
  }
}

__global__ __launch_bounds__(BLOCK, 2) void nerf_fused(
    const float* __restrict__ emb, const float* __restrict__ enc,
    const float* __restrict__ Win, const float* __restrict__ bin,
    const float* __restrict__ W0m, const float* __restrict__ b0v,
    const float* __restrict__ Wd, const float* __restrict__ bd,
    const float* __restrict__ Wc, const float* __restrict__ bc,
    const float* __restrict__ W1a, const float* __restrict__ b1a,
    const float* __restrict__ W1b, const float* __restrict__ b1b,
    const float* __restrict__ Wo, const float* __restrict__ bo,
    float* __restrict__ out, int npts)
{
  __shared__ __align__(16) _Float16 s_w[NFRAG * 512];   // 40 KB: [frag][lane][8]
  __shared__ __align__(16) float s_bias[352];

  const int tid = threadIdx.x;
  const int wib = tid >> 6;
  const int lane = tid & 63;
  const int q = lane >> 4;
  const int c = lane & 15;

  // --- stage biases: L1=0(64) L2=64 L3=128(16) L4=144 L5=208 L6=272 L7=336(16)
  for (int i = tid; i < 352; i += BLOCK) {
    float v;
    if (i < 64) v = bin[i];
    else if (i < 128) v = b0v[i - 64];
    else if (i < 144) v = bd[i - 128];
    else if (i < 208) v = bc[i - 144];
    else if (i < 272) v = b1a[i - 208];
    else if (i < 336) v = b1b[i - 272];
    else v = (i - 336 < 3) ? bo[i - 336] : 0.f;
    s_bias[i] = v;
  }

  // --- stage weight fragments (each of 4 waves handles 10 frags)
  for (int f = wib * 10; f < wib * 10 + 10; ++f) {
    half8 r = make_frag(f, q, c, Win, W0m, Wd, Wc, W1a, W1b, Wo);
    *(half8*)&s_w[f * 512 + lane * 8] = r;
  }

  __syncthreads();  // only barrier in the kernel

  const int totalWaves = gridDim.x * WAVES_PER_BLOCK;
  const int waveId = blockIdx.x * WAVES_PER_BLOCK + wib;
  const int ntiles = npts >> 5;  // 32 points per tile

  int tile = waveId;
  if (tile >= ntiles) return;

#define RW8(f) (*(const half8*)&s_w[(f) * 512 + lane * 8])
#define MM32(w, b, cc) __builtin_amdgcn_mfma_f32_16x16x32_f16((w), (b), (cc), 0, 0, 0)

  // prologue prefetch (two point groups g=0,1; point = tile*32 + 16g + c)
  float4v e0[2], e1[2];
  float4u na0[2], na1[2], e2p[2];
#pragma unroll
  for (int g = 0; g < 2; ++g) e2p[g] = (float4u){0.f, 0.f, 0.f, 0.f};
#pragma unroll
  for (int g = 0; g < 2; ++g) {
    const float* ep = emb + (size_t)(tile * 32 + 16 * g + c) * 32 + 8 * q;
    e0[g] = *(const float4v*)ep;
    e1[g] = *(const float4v*)(ep + 4);
    const float* np = enc + (size_t)(tile * 32 + 16 * g + c) * 39;
    na0[g] = *(const float4u*)(np + 8 * q);
    na1[g] = *(const float4u*)(np + 8 * q + 4);
    if (q == 0) e2p[g] = *(const float4u*)(np + 32);
    else if (q == 1) { e2p[g][0] = np[36]; e2p[g][1] = np[37]; e2p[g][2] = np[38]; }
  }

  float4v a_[4][2];  // layer accumulators
  half4 x[4][2];     // chained fragments: x[mb][g] = features 16mb+4q+r, point 16g+c

  // 64->64 layer: B1=concat(x0,x1), B2=concat(x2,x3); weights perm-staged.
#define LAYER64(FB, BOFF) do { \
    half8 b1_[2], b2_[2]; \
    _Pragma("unroll") for (int g = 0; g < 2; ++g) { \
      b1_[g] = CAT8(x[0][g], x[1][g]); \
      b2_[g] = CAT8(x[2][g], x[3][g]); \
    } \
    _Pragma("unroll") for (int mb = 0; mb < 4; ++mb) { \
      float4v bb = *(const float4v*)&s_bias[(BOFF) + 16 * mb + 4 * q]; \
      half8 w0 = RW8((FB) + 2 * mb), w1 = RW8((FB) + 2 * mb + 1); \
      _Pragma("unroll") for (int g = 0; g < 2; ++g) { \
        float4v a = MM32(w0, b1_[g], bb); \
        a_[mb][g] = MM32(w1, b2_[g], a); \
      } \
    } \
    _Pragma("unroll") for (int mb = 0; mb < 4; ++mb) \
      _Pragma("unroll") for (int g = 0; g < 2; ++g) { \
        half4 h; \
        _Pragma("unroll") for (int r = 0; r < 4; ++r) \
          h[r] = (_Float16)fmaxf(a_[mb][g][r], 0.f); \
        x[mb][g] = h; \
      } \
  } while (0)

  for (; tile < ntiles; tile += totalWaves) {
    const int nt0 = tile + totalWaves;
    const int nextTile = (nt0 < ntiles) ? nt0 : tile;

    // ---- L1: emb(32) -> 64, B straight from prefetched regs (standard k)
    half8 bfe[2];
#pragma unroll
    for (int g = 0; g < 2; ++g)
#pragma unroll
      for (int j = 0; j < 4; ++j) { bfe[g][j] = (_Float16)e0[g][j]; bfe[g][4 + j] = (_Float16)e1[g][j]; }
    {  // prefetch next emb
#pragma unroll
      for (int g = 0; g < 2; ++g) {
        const float* ep = emb + (size_t)(nextTile * 32 + 16 * g + c) * 32 + 8 * q;
        e0[g] = *(const float4v*)ep;
        e1[g] = *(const float4v*)(ep + 4);
      }
    }
#pragma unroll
    for (int mb = 0; mb < 4; ++mb) {
      float4v bb = *(const float4v*)&s_bias[0 + 16 * mb + 4 * q];
      half8 w = RW8(mb);
#pragma unroll
      for (int g = 0; g < 2; ++g) a_[mb][g] = MM32(w, bfe[g], bb);
    }
#pragma unroll
    for (int mb = 0; mb < 4; ++mb)
#pragma unroll
      for (int g = 0; g < 2; ++g) {
        half4 h;
#pragma unroll
        for (int r = 0; r < 4; ++r) h[r] = (_Float16)fmaxf(a_[mb][g][r], 0.f);
        x[mb][g] = h;
      }

    // ---- L2: 64 -> 64
    LAYER64(4, 64);

    // ---- L3: 64 -> 16 (dense + h), no relu; output chains into L4
    float dense_[2];
    half4 xh[2];
    {
      half8 w0 = RW8(12), w1 = RW8(13);
      float4v bb = *(const float4v*)&s_bias[128 + 4 * q];
#pragma unroll
      for (int g = 0; g < 2; ++g) {
        half8 b1_ = CAT8(x[0][g], x[1][g]);
        half8 b2_ = CAT8(x[2][g], x[3][g]);
        float4v a = MM32(w0, b1_, bb);
        a = MM32(w1, b2_, a);
        dense_[g] = a[0];  // valid in q==0 lanes (feature 0)
#pragma unroll
        for (int r = 0; r < 4; ++r) xh[g][r] = (_Float16)a[r];  // features 4q+r
      }
    }

    // enc B-frags straight from prefetched regs (no LDS)
    half8 xe32[2];
    half4 xe16[2];
#pragma unroll
    for (int g = 0; g < 2; ++g) {
#pragma unroll
      for (int j = 0; j < 4; ++j) { xe32[g][j] = (_Float16)na0[g][j]; xe32[g][4 + j] = (_Float16)na1[g][j]; }
#pragma unroll
      for (int i = 0; i < 4; ++i) xe16[g][i] = (_Float16)e2p[g][i];
    }
    {  // prefetch next enc
#pragma unroll
      for (int g = 0; g < 2; ++g) {
        const float* np = enc + (size_t)(nextTile * 32 + 16 * g + c) * 39;
        na0[g] = *(const float4u*)(np + 8 * q);
        na1[g] = *(const float4u*)(np + 8 * q + 4);
        if (q == 0) e2p[g] = *(const float4u*)(np + 32);
        else if (q == 1) { e2p[g][0] = np[36]; e2p[g][1] = np[37]; e2p[g][2] = np[38]; }
      }
    }

    // ---- L4: [h(16 slots) | enc(39, split 7+32)] -> 64
#pragma unroll
    for (int mb = 0; mb < 4; ++mb) {
      float4v bb = *(const float4v*)&s_bias[144 + 16 * mb + 4 * q];
      half8 wA = RW8(14 + 2 * mb), wE = RW8(15 + 2 * mb);
#pragma unroll
      for (int g = 0; g < 2; ++g) {
        half8 bh = CAT8(xh[g], xe16[g]);
        float4v a = MM32(wA, bh, bb);
        a_[mb][g] = MM32(wE, xe32[g], a);
      }
    }
#pragma unroll
    for (int mb = 0; mb < 4; ++mb)
#pragma unroll
      for (int g = 0; g < 2; ++g) {
        half4 h;
#pragma unroll
        for (int r = 0; r < 4; ++r) h[r] = (_Float16)fmaxf(a_[mb][g][r], 0.f);
        x[mb][g] = h;
      }

    // ---- L5, L6: 64 -> 64
    LAYER64(22, 208);
    LAYER64(30, 272);

    // ---- L7: 64 -> 3 (padded 16), no relu; store direct from q==0 lanes
    {
      half8 w0 = RW8(38), w1 = RW8(39);
      float4v bb = *(const float4v*)&s_bias[336 + 4 * q];
#pragma unroll
      for (int g = 0; g < 2; ++g) {
        half8 b1_ = CAT8(x[0][g], x[1][g]);
        half8 b2_ = CAT8(x[2][g], x[3][g]);
        float4v a = MM32(w0, b1_, bb);
        a = MM32(w1, b2_, a);
        if (q == 0) {
          float4v o;
          o[0] = a[0]; o[1] = a[1]; o[2] = a[2]; o[3] = dense_[g];
          *(float4v*)(out + (size_t)(tile * 32 + 16 * g + c) * 4) = o;
        }
      }
    }
  }
#undef LAYER64
#undef RW8
#undef MM32
}

extern "C" void kernel_launch(void* const* d_in, const int* in_sizes, int n_in,
                              void* d_out, int out_size, void* d_ws, size_t ws_size,
                              hipStream_t stream) {
  (void)d_ws; (void)ws_size; (void)out_size;
  if (n_in < 16) return;
  const float* emb = (const float*)d_in[0];
  const float* enc = (const float*)d_in[1];
  const float* Win = (const float*)d_in[2];
  const float* bin = (const float*)d_in[3];
  const float* W0m = (const float*)d_in[4];
  const float* b0v = (const float*)d_in[5];
  const float* Wd  = (const float*)d_in[6];
  const float* bd  = (const float*)d_in[7];
  const float* Wc  = (const float*)d_in[8];
  const float* bc  = (const float*)d_in[9];
  const float* W1a = (const float*)d_in[10];
  const float* b1a = (const float*)d_in[11];
  const float* W1b = (const float*)d_in[12];
  const float* b1b = (const float*)d_in[13];
  const float* Wo  = (const float*)d_in[14];
  const float* bo  = (const float*)d_in[15];
  float* out = (float*)d_out;
  const int npts = in_sizes[0] / 32;

  nerf_fused<<<GRID, BLOCK, 0, stream>>>(emb, enc, Win, bin, W0m, b0v, Wd, bd,
                                         Wc, bc, W1a, b1a, W1b, b1b, Wo, bo,
                                         out, npts);
}

// Round 5
// 429.686 us; speedup vs baseline: 1.7478x; 1.0505x over previous
//
#include <hip/hip_runtime.h>

// NeRF tiny MLP, fully fused. R7: same zero-LDS chaining algorithm as R6
// (passed, absmax 2e-3), attack the REMAINING SPILLS. R6 post-mortem:
// WRITE_SIZE 113MB vs 17MB true output + FETCH 547MB vs 300MB ideal = scratch
// spill traffic; allocator settled at the 128-VGPR bucket and spilled ~18
// regs. Live-range fixes (no algorithmic change):
//  1. x[4][2]+b1_/b2_ merged into xb1[2]/xb2[2] half8s written directly by
//     the relu/cvt epilogue (-16 regs, -8 movs/layer).
//  2. next-tile enc prefetch moved after L5 (was after L3): its 24 f32
//     staging regs are no longer live across the L4 pressure peak.
//  3. next-tile emb prefetch moved after L6 (was after L1): -16 regs of
//     whole-loop liveness; L6->L1 span still covers load latency.
// Derivation recap: D lane (q,c) holds (feature 16mb+4q+r, point c); a K=32
// B-frag lane (q,c) needs (k=8q+j, point c) -- same point class per lane, so
// chaining needs NO cross-lane movement: the CONSUMER layer's weight k-rows
// are permuted at staging: k-slot 32u+8q+j <-> feature 32u+16*(j>>2)+4q+(j&3).
// mfma 16x16x32 f16 layouts (q=lane>>4, c=lane&15) [HW-verified]:
//   A[m=c][k=8q+j]  B[k=8q+j][n=c]  D[row=4q+r][col=c]

#define WAVES_PER_BLOCK 4
#define BLOCK 256
#define GRID 1024
#define NFRAG 40

typedef _Float16 half8 __attribute__((ext_vector_type(8)));
typedef _Float16 half4 __attribute__((ext_vector_type(4)));
typedef float float4v __attribute__((ext_vector_type(4)));
typedef float float4u __attribute__((ext_vector_type(4), aligned(4)));  // enc rows only 4B-aligned

#define CAT8(a, b) __builtin_shufflevector((a), (b), 0, 1, 2, 3, 4, 5, 6, 7)

// k-slot (32u + 8q + j) -> logical input-feature index, for layers whose
// input is a chained MFMA output consumed as (xb1, xb2).
__device__ __forceinline__ int permk(int u, int q, int j) {
  return 32 * u + 16 * (j >> 2) + 4 * q + (j & 3);
}

// Weight fragment catalog (16B/lane slots in s_w), all K=32 A-frags:
//  f 0..3   L1  Win (32x64)  standard k:   Win[(8q+j)*64 + 16f + c]
//  f 4..11  L2  W0m (64x64)  perm k:       W0m[permk(u,q,j)*64 + 16mb + c]
//  f 12..13 L3  Wd  (64x16)  perm k:       Wd[permk(u,q,j)*16 + c]
//  f 14..21 L4  Wc  (54x64)  (mb,u):
//     u=0 pairs B1=concat(xh, xe16): j<4: h-slot hs=4q+j (hs==0 is the dense
//         slot -> zero row; else Wc[hs-1]); j>=4: e=32+4q+(j-4): e<39 ->
//         Wc[15+e] else 0.
//     u=1 pairs B2=xe32 (enc feats 8q+j): Wc[(15+8q+j)*64 + 16mb + c]
//  f 22..29 L5  W1a perm k | f 30..37 L6  W1b perm k
//  f 38..39 L7  Wo  (64x3)  perm k, cols padded 3->16
__device__ half8 make_frag(int f, int q, int c,
                           const float* Win, const float* W0m, const float* Wd,
                           const float* Wc, const float* W1a, const float* W1b,
                           const float* Wo) {
  half8 r;
  if (f < 4) {
#pragma unroll
    for (int j = 0; j < 8; ++j)
      r[j] = (_Float16)Win[(size_t)(8 * q + j) * 64 + 16 * f + c];
    return r;
  }
  if (f < 12) {
    int mb = (f - 4) >> 1, u = (f - 4) & 1;
#pragma unroll
    for (int j = 0; j < 8; ++j)
      r[j] = (_Float16)W0m[(size_t)permk(u, q, j) * 64 + 16 * mb + c];
    return r;
  }
  if (f < 14) {
    int u = f - 12;
#pragma unroll
    for (int j = 0; j < 8; ++j)
      r[j] = (_Float16)Wd[(size_t)permk(u, q, j) * 16 + c];
    return r;
  }
  if (f < 22) {
    int mb = (f - 14) >> 1, u = (f - 14) & 1;
    if (u == 0) {
#pragma unroll
      for (int i = 0; i < 4; ++i) {
        int hs = 4 * q + i;           // h-slot: 0 is dense -> zero weight row
        r[i] = (hs == 0) ? (_Float16)0.f
                         : (_Float16)Wc[(size_t)(hs - 1) * 64 + 16 * mb + c];
        int e = 32 + 4 * q + i;       // enc features 32..38, pad 0
        r[4 + i] = (e < 39) ? (_Float16)Wc[(size_t)(15 + e) * 64 + 16 * mb + c]
                            : (_Float16)0.f;
      }
    } else {
#pragma unroll
      for (int j = 0; j < 8; ++j)     // enc features 0..31
        r[j] = (_Float16)Wc[(size_t)(15 + 8 * q + j) * 64 + 16 * mb + c];
    }
    return r;
  }
  if (f < 30) {
    int mb = (f - 22) >> 1, u = (f - 22) & 1;
#pragma unroll
    for (int j = 0; j < 8; ++j)
      r[j] = (_Float16)W1a[(size_t)permk(u, q, j) * 64 + 16 * mb + c];
    return r;
  }
  if (f < 38) {
    int mb = (f - 30) >> 1, u = (f - 30) & 1;
#pragma unroll
    for (int j = 0; j < 8; ++j)
      r[j] = (_Float16)W1b[(size_t)permk(u, q, j) * 64 + 16 * mb + c];
    return r;
  }
  {
    int u = f - 38;
#pragma unroll
    for (int j = 0; j < 8; ++j)
      r[j] = (c < 3) ? (_Float16)Wo[(size_t)permk(u, q, j) * 3 + c]
                     : (_Float16)0.f;
    return r;
  }
}

__global__ __launch_bounds__(BLOCK, 2) void nerf_fused(
    const float* __restrict__ emb, const float* __restrict__ enc,
    const float* __restrict__ Win, const float* __restrict__ bin,
    const float* __restrict__ W0m, const float* __restrict__ b0v,
    const float* __restrict__ Wd, const float* __restrict__ bd,
    const float* __restrict__ Wc, const float* __restrict__ bc,
    const float* __restrict__ W1a, const float* __restrict__ b1a,
    const float* __restrict__ W1b, const float* __restrict__ b1b,
    const float* __restrict__ Wo, const float* __restrict__ bo,
    float* __restrict__ out, int npts)
{
  __shared__ __align__(16) _Float16 s_w[NFRAG * 512];   // 40 KB: [frag][lane][8]
  __shared__ __align__(16) float s_bias[352];

  const int tid = threadIdx.x;
  const int wib = tid >> 6;
  const int lane = tid & 63;
  const int q = lane >> 4;
  const int c = lane & 15;

  // --- stage biases: L1=0(64) L2=64 L3=128(16) L4=144 L5=208 L6=272 L7=336(16)
  for (int i = tid; i < 352; i += BLOCK) {
    float v;
    if (i < 64) v = bin[i];
    else if (i < 128) v = b0v[i - 64];
    else if (i < 144) v = bd[i - 128];
    else if (i < 208) v = bc[i - 144];
    else if (i < 272) v = b1a[i - 208];
    else if (i < 336) v = b1b[i - 272];
    else v = (i - 336 < 3) ? bo[i - 336] : 0.f;
    s_bias[i] = v;
  }

  // --- stage weight fragments (each of 4 waves handles 10 frags)
  for (int f = wib * 10; f < wib * 10 + 10; ++f) {
    half8 r = make_frag(f, q, c, Win, W0m, Wd, Wc, W1a, W1b, Wo);
    *(half8*)&s_w[f * 512 + lane * 8] = r;
  }

  __syncthreads();  // only barrier in the kernel

  const int totalWaves = gridDim.x * WAVES_PER_BLOCK;
  const int waveId = blockIdx.x * WAVES_PER_BLOCK + wib;
  const int ntiles = npts >> 5;  // 32 points per tile

  int tile = waveId;
  if (tile >= ntiles) return;

#define RW8(f) (*(const half8*)&s_w[(f) * 512 + lane * 8])
#define MM32(w, b, cc) __builtin_amdgcn_mfma_f32_16x16x32_f16((w), (b), (cc), 0, 0, 0)

  // prologue prefetch (two point groups g=0,1; point = tile*32 + 16g + c)
  float4v e0[2], e1[2];
  float4u na0[2], na1[2], e2p[2];
#pragma unroll
  for (int g = 0; g < 2; ++g) e2p[g] = (float4u){0.f, 0.f, 0.f, 0.f};
#pragma unroll
  for (int g = 0; g < 2; ++g) {
    const float* ep = emb + (size_t)(tile * 32 + 16 * g + c) * 32 + 8 * q;
    e0[g] = *(const float4v*)ep;
    e1[g] = *(const float4v*)(ep + 4);
    const float* np = enc + (size_t)(tile * 32 + 16 * g + c) * 39;
    na0[g] = *(const float4u*)(np + 8 * q);
    na1[g] = *(const float4u*)(np + 8 * q + 4);
    if (q == 0) e2p[g] = *(const float4u*)(np + 32);
    else if (q == 1) { e2p[g][0] = np[36]; e2p[g][1] = np[37]; e2p[g][2] = np[38]; }
  }

  float4v a_[4][2];       // layer accumulators
  half8 xb1[2], xb2[2];   // chained B-fragments (written directly by epilogues)

  // Epilogue: relu+cvt a_[0..3][g] directly into the two B-fragments.
  // xb1 element j = feature 16*(j>>2)+4q+(j&3); xb2 = +32 (permk staging).
#define EPILOGUE_RELU() do { \
    _Pragma("unroll") for (int g = 0; g < 2; ++g) { \
      half8 v1, v2; \
      _Pragma("unroll") for (int r = 0; r < 4; ++r) { \
        v1[r]     = (_Float16)fmaxf(a_[0][g][r], 0.f); \
        v1[4 + r] = (_Float16)fmaxf(a_[1][g][r], 0.f); \
        v2[r]     = (_Float16)fmaxf(a_[2][g][r], 0.f); \
        v2[4 + r] = (_Float16)fmaxf(a_[3][g][r], 0.f); \
      } \
      xb1[g] = v1; xb2[g] = v2; \
    } \
  } while (0)

  // 64->64 layer: consumes xb1/xb2, produces xb1/xb2 (weights perm-staged).
#define LAYER64(FB, BOFF) do { \
    _Pragma("unroll") for (int mb = 0; mb < 4; ++mb) { \
      float4v bb = *(const float4v*)&s_bias[(BOFF) + 16 * mb + 4 * q]; \
      half8 w0 = RW8((FB) + 2 * mb), w1 = RW8((FB) + 2 * mb + 1); \
      _Pragma("unroll") for (int g = 0; g < 2; ++g) { \
        float4v a = MM32(w0, xb1[g], bb); \
        a_[mb][g] = MM32(w1, xb2[g], a); \
      } \
    } \
    EPILOGUE_RELU(); \
  } while (0)

  for (; tile < ntiles; tile += totalWaves) {
    const int nt0 = tile + totalWaves;
    const int nextTile = (nt0 < ntiles) ? nt0 : tile;

    // ---- L1: emb(32) -> 64, B straight from prefetched regs (standard k)
    half8 bfe[2];
#pragma unroll
    for (int g = 0; g < 2; ++g)
#pragma unroll
      for (int j = 0; j < 4; ++j) { bfe[g][j] = (_Float16)e0[g][j]; bfe[g][4 + j] = (_Float16)e1[g][j]; }
#pragma unroll
    for (int mb = 0; mb < 4; ++mb) {
      float4v bb = *(const float4v*)&s_bias[0 + 16 * mb + 4 * q];
      half8 w = RW8(mb);
#pragma unroll
      for (int g = 0; g < 2; ++g) a_[mb][g] = MM32(w, bfe[g], bb);
    }
    EPILOGUE_RELU();

    // ---- L2: 64 -> 64
    LAYER64(4, 64);

    // ---- L3: 64 -> 16 (dense + h), no relu; output chains into L4
    float dense_[2];
    half4 xh[2];
    {
      half8 w0 = RW8(12), w1 = RW8(13);
      float4v bb = *(const float4v*)&s_bias[128 + 4 * q];
#pragma unroll
      for (int g = 0; g < 2; ++g) {
        float4v a = MM32(w0, xb1[g], bb);
        a = MM32(w1, xb2[g], a);
        dense_[g] = a[0];  // valid in q==0 lanes (feature 0)
#pragma unroll
        for (int r = 0; r < 4; ++r) xh[g][r] = (_Float16)a[r];  // features 4q+r
      }
    }

    // enc B-frags straight from prefetched regs (no LDS); frees na*/e2p
    half8 xe32[2];
    half4 xe16[2];
#pragma unroll
    for (int g = 0; g < 2; ++g) {
#pragma unroll
      for (int j = 0; j < 4; ++j) { xe32[g][j] = (_Float16)na0[g][j]; xe32[g][4 + j] = (_Float16)na1[g][j]; }
#pragma unroll
      for (int i = 0; i < 4; ++i) xe16[g][i] = (_Float16)e2p[g][i];
    }

    // ---- L4: [h(16 slots) | enc(39, split 7+32)] -> 64
#pragma unroll
    for (int mb = 0; mb < 4; ++mb) {
      float4v bb = *(const float4v*)&s_bias[144 + 16 * mb + 4 * q];
      half8 wA = RW8(14 + 2 * mb), wE = RW8(15 + 2 * mb);
#pragma unroll
      for (int g = 0; g < 2; ++g) {
        half8 bh = CAT8(xh[g], xe16[g]);
        float4v a = MM32(wA, bh, bb);
        a_[mb][g] = MM32(wE, xe32[g], a);
      }
    }
    EPILOGUE_RELU();

    // ---- L5: 64 -> 64
    LAYER64(22, 208);

    // prefetch next enc AFTER L5: in-flight span L5 -> next-iter L4, and the
    // 24 f32 staging regs are dead across the L2-L4 pressure peak.
#pragma unroll
    for (int g = 0; g < 2; ++g) {
      const float* np = enc + (size_t)(nextTile * 32 + 16 * g + c) * 39;
      na0[g] = *(const float4u*)(np + 8 * q);
      na1[g] = *(const float4u*)(np + 8 * q + 4);
      if (q == 0) e2p[g] = *(const float4u*)(np + 32);
      else if (q == 1) { e2p[g][0] = np[36]; e2p[g][1] = np[37]; e2p[g][2] = np[38]; }
    }

    // ---- L6: 64 -> 64
    LAYER64(30, 272);

    // prefetch next emb AFTER L6: span L6 -> next-iter L1.
#pragma unroll
    for (int g = 0; g < 2; ++g) {
      const float* ep = emb + (size_t)(nextTile * 32 + 16 * g + c) * 32 + 8 * q;
      e0[g] = *(const float4v*)ep;
      e1[g] = *(const float4v*)(ep + 4);
    }

    // ---- L7: 64 -> 3 (padded 16), no relu; store direct from q==0 lanes
    {
      half8 w0 = RW8(38), w1 = RW8(39);
      float4v bb = *(const float4v*)&s_bias[336 + 4 * q];
#pragma unroll
      for (int g = 0; g < 2; ++g) {
        float4v a = MM32(w0, xb1[g], bb);
        a = MM32(w1, xb2[g], a);
        if (q == 0) {
          float4v o;
          o[0] = a[0]; o[1] = a[1]; o[2] = a[2]; o[3] = dense_[g];
          *(float4v*)(out + (size_t)(tile * 32 + 16 * g + c) * 4) = o;
        }
      }
    }
  }
#undef LAYER64
#undef EPILOGUE_RELU
#undef RW8
#undef MM32
}

extern "C" void kernel_launch(void* const* d_in, const int* in_sizes, int n_in,
                              void* d_out, int out_size, void* d_ws, size_t ws_size,
                              hipStream_t stream) {
  (void)d_ws; (void)ws_size; (void)out_size;
  if (n_in < 16) return;
  const float* emb = (const float*)d_in[0];
  const float* enc = (const float*)d_in[1];
  const float* Win = (const float*)d_in[2];
  const float* bin = (const float*)d_in[3];
  const float* W0m = (const float*)d_in[4];
  const float* b0v = (const float*)d_in[5];
  const float* Wd  = (const float*)d_in[6];
  const float* bd  = (const float*)d_in[7];
  const float* Wc  = (const float*)d_in[8];
  const float* bc  = (const float*)d_in[9];
  const float* W1a = (const float*)d_in[10];
  const float* b1a = (const float*)d_in[11];
  const float* W1b = (const float*)d_in[12];
  const float* b1b = (const float*)d_in[13];
  const float* Wo  = (const float*)d_in[14];
  const float* bo  = (const float*)d_in[15];
  float* out = (float*)d_out;
  const int npts = in_sizes[0] / 32;

  nerf_fused<<<GRID, BLOCK, 0, stream>>>(emb, enc, Win, bin, W0m, b0v, Wd, bd,
                                         Wc, bc, W1a, b1a, W1b, b1b, Wo, bo,
                                         out, npts);
}